// Round 14
// baseline (125.148 us; speedup 1.0000x reference)
//
#include <hip/hip_runtime.h>

// Problem constants (B=8, V=8192, N=2048, C=128)
#define BB 8
#define VV 8192
#define NN 2048
#define CC 128
#define SEL_LD 34   // 32-row selT tile leading dim

// ---------------------------------------------------------------------------
// K0: blocks [0,512)  : MLP over B*N rows (32 rows/block)  -> mlp_out
//     blocks [512,544): qpt producer {px,py,pz,sp} per (b,n) -> qpt (global)
// sp uses the EXACT reference rounding (proven in r5): (rn(px^2)+rn(py^2))+rn(pz^2)
// ---------------------------------------------------------------------------
__global__ __launch_bounds__(512) void mlp_qpt_kernel(
    const float* __restrict__ processed, const float* __restrict__ W1,
    const float* __restrict__ b1, const float* __restrict__ W2,
    const float* __restrict__ b2, const float* __restrict__ graph_pos,
    float* __restrict__ mlp_out, float4* __restrict__ qpt)
{
    const int t = threadIdx.x;

    if (blockIdx.x >= 512) {
        // ---- qpt producer: 32 blocks x 512 thr x 1 point ----
        const int p = (blockIdx.x - 512) * 512 + t;     // 0..16383 = b*NN+n
        const float* g3 = graph_pos + 3 * (size_t)p;
        float px = g3[0], py = g3[1], pz = g3[2];
        float sp = __fadd_rn(__fadd_rn(__fmul_rn(px, px), __fmul_rn(py, py)),
                             __fmul_rn(pz, pz));
        qpt[p] = make_float4(px, py, pz, sp);
        return;                                          // block-uniform exit
    }

    // ---- MLP block (r13-proven): 32 rows, 2x4 micro-tile ----
    __shared__ float selT[CC * SEL_LD];
    const int row0 = blockIdx.x * 32;

    #pragma unroll
    for (int i = 0; i < 8; ++i) {
        int flat = i * 512 + t;           // 0..4095
        int r = flat >> 7;                // 0..31
        int k = flat & 127;
        selT[k * SEL_LD + r] = processed[(size_t)(row0 + r) * CC + k];
    }
    __syncthreads();

    const int g = t & 31;
    const int rb = t >> 5;                // 0..15
    const int c0 = g * 4;
    const int r0 = rb * 2;

    float acc[2][4] = {{0.f, 0.f, 0.f, 0.f}, {0.f, 0.f, 0.f, 0.f}};
    #pragma unroll 4
    for (int k = 0; k < CC; ++k) {
        float4 wv = *(const float4*)(W1 + k * CC + c0);
        float2 av = *(const float2*)(&selT[k * SEL_LD + r0]);
        acc[0][0] = fmaf(av.x, wv.x, acc[0][0]);
        acc[0][1] = fmaf(av.x, wv.y, acc[0][1]);
        acc[0][2] = fmaf(av.x, wv.z, acc[0][2]);
        acc[0][3] = fmaf(av.x, wv.w, acc[0][3]);
        acc[1][0] = fmaf(av.y, wv.x, acc[1][0]);
        acc[1][1] = fmaf(av.y, wv.y, acc[1][1]);
        acc[1][2] = fmaf(av.y, wv.z, acc[1][2]);
        acc[1][3] = fmaf(av.y, wv.w, acc[1][3]);
    }

    float4 b1v = *(const float4*)(b1 + c0);
    float4 w2v = *(const float4*)(W2 + c0);
    float bias2 = b2[0];

    #pragma unroll
    for (int i = 0; i < 2; ++i) {
        float h0 = acc[i][0] + b1v.x; h0 = h0 > 0.f ? h0 : 0.f;
        float h1 = acc[i][1] + b1v.y; h1 = h1 > 0.f ? h1 : 0.f;
        float h2 = acc[i][2] + b1v.z; h2 = h2 > 0.f ? h2 : 0.f;
        float h3 = acc[i][3] + b1v.w; h3 = h3 > 0.f ? h3 : 0.f;
        float p = fmaf(h0, w2v.x, fmaf(h1, w2v.y, fmaf(h2, w2v.z, h3 * w2v.w)));
        #pragma unroll
        for (int off = 1; off < 32; off <<= 1) p += __shfl_xor(p, off, 64);
        if (g == 0) mlp_out[row0 + r0 + i] = p + bias2;
    }
}

// ---------------------------------------------------------------------------
// K1: argmin-only. 256 blocks x 512 thr = exactly 1 block/CU, 256 verts/block.
// Wave w scans chunk [w*256,(w+1)*256) of qpt via WAVE-UNIFORM s_load_dwordx4
// (scalar pipe) — zero LDS traffic, zero VALU for data movement; each VALU op
// reads Q components as its one allowed SGPR operand. Vt=4 verts/lane gives
// 64 VALU-cyc per point; unroll-4 keeps 4 s_loads in flight (~200cyc latency
// covered by ~256cyc compute). LDS = 12 KB merge scratch only.
// Bit-exact reference rounding (frozen since round 4):
//   e2 = fma(2vz,pz, fma(2vy,py, rn(2vx*px))) == rn(2e)   (2x exact)
//   d2 = rn(rn(sv - e2) + sp)
//   strict < + ascending chunk merge -> first-index tie-break.
// ---------------------------------------------------------------------------
__global__ __launch_bounds__(512, 4) void argmin_kernel(
    const float* __restrict__ verts, const float4* __restrict__ qpt,
    unsigned short* __restrict__ idx_out)
{
    __shared__ float sd[8 * 256];           // 8 KB
    __shared__ unsigned short si[8 * 256];  // 4 KB

    const int bid = blockIdx.x;             // 256 blocks
    const int b = bid >> 5;                 // 32 blocks per batch
    const int v0 = (bid & 31) * 256;
    const int t = threadIdx.x;
    const int lane = t & 63;
    const int w = __builtin_amdgcn_readfirstlane(t >> 6);   // wave id 0..7

    // vertex registers (Vt=4 per lane)
    float sv[4], tx[4], ty[4], tz[4];
    #pragma unroll
    for (int j = 0; j < 4; ++j) {
        int v = v0 + j * 64 + lane;
        const float* vp = verts + ((size_t)b * VV + v) * 3;
        float x = vp[0], y = vp[1], z = vp[2];
        sv[j] = __fadd_rn(__fadd_rn(__fmul_rn(x, x), __fmul_rn(y, y)),
                          __fmul_rn(z, z));
        tx[j] = x + x; ty[j] = y + y; tz[j] = z + z;   // exact 2x
    }

    // scan: wave-uniform pointer -> scalar loads
    const float4* q = qpt + (size_t)b * NN + (size_t)w * 256;
    float best[4] = {3.4e38f, 3.4e38f, 3.4e38f, 3.4e38f};
    int bi[4] = {0, 0, 0, 0};
    #pragma unroll 4
    for (int n = 0; n < 256; ++n) {
        float4 Q = q[n];   // s_load_dwordx4 (uniform addr, scalar pipe)
        #pragma unroll
        for (int j = 0; j < 4; ++j) {
            float e2 = fmaf(tz[j], Q.z, fmaf(ty[j], Q.y, __fmul_rn(tx[j], Q.x)));
            float d2 = __fadd_rn(__fsub_rn(sv[j], e2), Q.w);
            if (d2 < best[j]) { best[j] = d2; bi[j] = n; }  // strict <: first idx
        }
    }

    #pragma unroll
    for (int j = 0; j < 4; ++j) {
        sd[w * 256 + j * 64 + lane] = best[j];
        si[w * 256 + j * 64 + lane] = (unsigned short)(bi[j] + w * 256);
    }
    __syncthreads();

    if (t < 256) {
        float bb = sd[t];
        int   ii = si[t];
        #pragma unroll
        for (int c = 1; c < 8; ++c) {       // ascending chunks: first-index ties
            float d = sd[c * 256 + t];
            int   i = si[c * 256 + t];
            if (d < bb) { bb = d; ii = i; }
        }
        idx_out[(size_t)b * VV + v0 + t] = (unsigned short)ii;
    }
}

// K2: out[b,v] = mlp_out[b*NN + idx[b,v]]. mlp_out is 8 KB/batch -> L2 hot.
__global__ __launch_bounds__(256) void gather_kernel(
    const float* __restrict__ mlp_out, const unsigned short* __restrict__ idx,
    float* __restrict__ out)
{
    const int gid = blockIdx.x * 256 + threadIdx.x;   // 0..65535
    const int b = gid >> 13;                          // / VV
    out[gid] = mlp_out[b * NN + (int)idx[gid]];
}

extern "C" void kernel_launch(void* const* d_in, const int* in_sizes, int n_in,
                              void* d_out, int out_size, void* d_ws, size_t ws_size,
                              hipStream_t stream) {
    const float* verts     = (const float*)d_in[0];
    const float* graph_pos = (const float*)d_in[1];
    const float* processed = (const float*)d_in[2];
    const float* W1        = (const float*)d_in[3];
    const float* b1        = (const float*)d_in[4];
    const float* W2        = (const float*)d_in[5];
    const float* b2        = (const float*)d_in[6];
    float* out = (float*)d_out;

    float* mlp_out       = (float*)d_ws;                                   // 64 KB
    float4* qpt          = (float4*)((char*)d_ws + (BB * NN * 4));         // 256 KB
    unsigned short* idxb = (unsigned short*)((char*)d_ws + (BB * NN * 4) + (BB * NN * 16)); // 128 KB

    hipLaunchKernelGGL(mlp_qpt_kernel, dim3(544), dim3(512), 0, stream,
                       processed, W1, b1, W2, b2, graph_pos, mlp_out, qpt);
    hipLaunchKernelGGL(argmin_kernel, dim3(256), dim3(512), 0, stream,
                       verts, qpt, idxb);
    hipLaunchKernelGGL(gather_kernel, dim3((BB * VV) / 256), dim3(256), 0, stream,
                       mlp_out, idxb, out);
}

// Round 15
// 108.085 us; speedup vs baseline: 1.1579x; 1.1579x over previous
//
#include <hip/hip_runtime.h>

// Problem constants (B=8, V=8192, N=2048, C=128)
#define BB 8
#define VV 8192
#define NN 2048
#define CC 128
#define SEL_LD 34   // 32-row selT tile leading dim
#define HALF 1024   // points per argmin block (N split in 2)

// Shared memory (33 KB -> 4 blocks/CU, 32 waves/CU):
//   pts[1024] float4        : 16 KB   (argmin blocks: this half's points)
//   union {
//     selT[128*34] float    : 17 KB   (MLP blocks)
//     { sd, si }            : 12 KB   (argmin merge scratch: 8 chunks x 256)
//   }
struct MergeScratch {
    float sd[8 * 256];
    unsigned short si[8 * 256];
};
union SelOrMerge {
    float selT[CC * SEL_LD];
    MergeScratch m;
};

// K1, 1024 blocks x 512 thr, block-specialized, N-split:
//   blocks [0,512)    : argmin of 256 verts over HALF the points -> cand (uint2)
//                       (vg = bid>>1 vertex-group, h = bid&1 point-half;
//                        8 waves x 128-pt chunks, Vt=4 verts/lane)
//   blocks [512,1024) : MLP for 32 rows each -> mlp_out
// 33 KB/block -> 4 blocks/CU: argmin waves/SIMD rises 2 -> ~4 (vs r13), the
// axis not yet tested; VALU-idle from ds_read/W1 latency gets more TLP cover.
// Bit-exact reference rounding (frozen since round 4):
//   sp = (rn(px^2)+rn(py^2))+rn(pz^2)
//   e2 = fma(2vz,pz, fma(2vy,py, rn(2vx*px))) == rn(2e)   (2x exact)
//   d2 = rn(rn(sv - e2) + sp)
//   strict < + ascending chunk merge -> first-index tie-break (within half).
__global__ __launch_bounds__(512, 8) void argmin_mlp_kernel(
    const float* __restrict__ verts, const float* __restrict__ graph_pos,
    const float* __restrict__ processed, const float* __restrict__ W1,
    const float* __restrict__ b1, const float* __restrict__ W2,
    const float* __restrict__ b2, float* __restrict__ mlp_out,
    uint2* __restrict__ cand)
{
    __shared__ float4 pts[HALF];      // 16 KB
    __shared__ SelOrMerge u;          // 17 KB

    const int t = threadIdx.x;
    const int lane = t & 63;
    const int w = __builtin_amdgcn_readfirstlane(t >> 6);   // wave id 0..7

    if (blockIdx.x < 512) {
        // ================= ARGMIN BLOCK (one point-half) =================
        const int vg = blockIdx.x >> 1;   // vertex group 0..255
        const int h  = blockIdx.x & 1;    // point half 0/1
        const int b  = vg >> 5;           // 32 groups per batch
        const int v0 = (vg & 31) * 256;

        // stage this half's 1024 points with exact sp
        #pragma unroll
        for (int i = 0; i < 2; ++i) {
            int p = t + i * 512;          // 0..1023
            const float* g3 = graph_pos + ((size_t)b * NN + h * HALF + p) * 3;
            float px = g3[0], py = g3[1], pz = g3[2];
            float sp = __fadd_rn(__fadd_rn(__fmul_rn(px, px), __fmul_rn(py, py)),
                                 __fmul_rn(pz, pz));
            pts[p] = make_float4(px, py, pz, sp);
        }

        // vertex registers (Vt=4 per lane)
        float sv[4], tx[4], ty[4], tz[4];
        #pragma unroll
        for (int j = 0; j < 4; ++j) {
            int v = v0 + j * 64 + lane;
            const float* vp = verts + ((size_t)b * VV + v) * 3;
            float x = vp[0], y = vp[1], z = vp[2];
            sv[j] = __fadd_rn(__fadd_rn(__fmul_rn(x, x), __fmul_rn(y, y)),
                              __fmul_rn(z, z));
            tx[j] = x + x; ty[j] = y + y; tz[j] = z + z;   // exact 2x
        }
        __syncthreads();

        // scan: wave w covers chunk [w*128, w*128+128) of this half
        const float4* P = &pts[w * 128];
        float best[4] = {3.4e38f, 3.4e38f, 3.4e38f, 3.4e38f};
        int bi[4] = {0, 0, 0, 0};
        #pragma unroll 4
        for (int n = 0; n < 128; ++n) {
            float4 Q = P[n];   // ds_read_b128, same-addr broadcast (conflict-free)
            #pragma unroll
            for (int j = 0; j < 4; ++j) {
                float e2 = fmaf(tz[j], Q.z, fmaf(ty[j], Q.y, __fmul_rn(tx[j], Q.x)));
                float d2 = __fadd_rn(__fsub_rn(sv[j], e2), Q.w);
                if (d2 < best[j]) { best[j] = d2; bi[j] = n; }  // strict <: first idx
            }
        }

        __syncthreads();   // safe to alias u as merge scratch (selT untouched here)
        #pragma unroll
        for (int j = 0; j < 4; ++j) {
            u.m.sd[w * 256 + j * 64 + lane] = best[j];
            u.m.si[w * 256 + j * 64 + lane] = (unsigned short)(bi[j] + w * 128);
        }
        __syncthreads();

        if (t < 256) {
            float bb = u.m.sd[t];
            int   ii = u.m.si[t];
            #pragma unroll
            for (int c = 1; c < 8; ++c) {       // ascending chunks: first-index ties
                float d = u.m.sd[c * 256 + t];
                int   i = u.m.si[c * 256 + t];
                if (d < bb) { bb = d; ii = i; }
            }
            cand[(size_t)h * (BB * VV) + (size_t)b * VV + v0 + t] =
                make_uint2(__float_as_uint(bb), (unsigned)(h * HALF + ii));
        }
    } else {
        // ================= MLP BLOCK (32 rows, r13-proven) =================
        const int mb = blockIdx.x - 512;      // 0..511
        const int row0 = mb * 32;

        #pragma unroll
        for (int i = 0; i < 8; ++i) {
            int flat = i * 512 + t;           // 0..4095
            int r = flat >> 7;                // 0..31
            int k = flat & 127;
            u.selT[k * SEL_LD + r] = processed[(size_t)(row0 + r) * CC + k];
        }
        __syncthreads();

        const int g = t & 31;                 // col group: 4 cols
        const int rb = t >> 5;                // row group: 2 rows, 0..15
        const int c0 = g * 4;
        const int r0 = rb * 2;

        float acc[2][4] = {{0.f, 0.f, 0.f, 0.f}, {0.f, 0.f, 0.f, 0.f}};
        #pragma unroll 4
        for (int k = 0; k < CC; ++k) {
            float4 wv = *(const float4*)(W1 + k * CC + c0);
            float2 av = *(const float2*)(&u.selT[k * SEL_LD + r0]);
            acc[0][0] = fmaf(av.x, wv.x, acc[0][0]);
            acc[0][1] = fmaf(av.x, wv.y, acc[0][1]);
            acc[0][2] = fmaf(av.x, wv.z, acc[0][2]);
            acc[0][3] = fmaf(av.x, wv.w, acc[0][3]);
            acc[1][0] = fmaf(av.y, wv.x, acc[1][0]);
            acc[1][1] = fmaf(av.y, wv.y, acc[1][1]);
            acc[1][2] = fmaf(av.y, wv.z, acc[1][2]);
            acc[1][3] = fmaf(av.y, wv.w, acc[1][3]);
        }

        float4 b1v = *(const float4*)(b1 + c0);
        float4 w2v = *(const float4*)(W2 + c0);
        float bias2 = b2[0];

        #pragma unroll
        for (int i = 0; i < 2; ++i) {
            float h0 = acc[i][0] + b1v.x; h0 = h0 > 0.f ? h0 : 0.f;
            float h1 = acc[i][1] + b1v.y; h1 = h1 > 0.f ? h1 : 0.f;
            float h2 = acc[i][2] + b1v.z; h2 = h2 > 0.f ? h2 : 0.f;
            float h3 = acc[i][3] + b1v.w; h3 = h3 > 0.f ? h3 : 0.f;
            float p = fmaf(h0, w2v.x, fmaf(h1, w2v.y, fmaf(h2, w2v.z, h3 * w2v.w)));
            // reduce across the 32 col-lanes (xor offsets <32 stay in half-wave)
            #pragma unroll
            for (int off = 1; off < 32; off <<= 1) p += __shfl_xor(p, off, 64);
            if (g == 0) mlp_out[row0 + r0 + i] = p + bias2;
        }
    }
}

// K2: combine the two half-candidates (half0 first + strict < == global
// first-index tie-break) and gather mlp_out. Everything L2-hot.
__global__ __launch_bounds__(256) void gather_kernel(
    const float* __restrict__ mlp_out, const uint2* __restrict__ cand,
    float* __restrict__ out)
{
    const int gid = blockIdx.x * 256 + threadIdx.x;   // 0..65535
    const int b = gid >> 13;                          // / VV
    uint2 c0 = cand[gid];
    uint2 c1 = cand[BB * VV + gid];
    float d0 = __uint_as_float(c0.x);
    float d1 = __uint_as_float(c1.x);
    unsigned ii = (d1 < d0) ? c1.y : c0.y;            // strict: half0 wins ties
    out[gid] = mlp_out[b * NN + (int)ii];
}

extern "C" void kernel_launch(void* const* d_in, const int* in_sizes, int n_in,
                              void* d_out, int out_size, void* d_ws, size_t ws_size,
                              hipStream_t stream) {
    const float* verts     = (const float*)d_in[0];
    const float* graph_pos = (const float*)d_in[1];
    const float* processed = (const float*)d_in[2];
    const float* W1        = (const float*)d_in[3];
    const float* b1        = (const float*)d_in[4];
    const float* W2        = (const float*)d_in[5];
    const float* b2        = (const float*)d_in[6];
    float* out = (float*)d_out;

    float* mlp_out = (float*)d_ws;                              // 64 KB
    uint2* cand    = (uint2*)((char*)d_ws + BB * NN * 4);       // 2 x 512 KB

    hipLaunchKernelGGL(argmin_mlp_kernel, dim3(1024), dim3(512), 0, stream,
                       verts, graph_pos, processed, W1, b1, W2, b2,
                       mlp_out, cand);
    hipLaunchKernelGGL(gather_kernel, dim3((BB * VV) / 256), dim3(256), 0, stream,
                       mlp_out, cand, out);
}

// Round 16
// 107.177 us; speedup vs baseline: 1.1677x; 1.0085x over previous
//
#include <hip/hip_runtime.h>

// Problem constants (B=8, V=8192, N=2048, C=128)
#define BB 8
#define VV 8192
#define NN 2048
#define CC 128
#define SEL_LD 34   // 32-row selT tile leading dim
#define HALF 1024   // points per argmin block (N split in 2)

// Shared memory (~41 KB -> 3 blocks/CU under launch_bounds(512,6)):
//   pts[1024] float4        : 16 KB   (argmin blocks: this half's points)
//   union {
//     selT[128*34] float    : 17 KB   (MLP blocks)
//     { sd, si } 8x512      : 24 KB   (argmin merge scratch)
//   }
struct MergeScratch {
    float sd[8 * 512];
    unsigned short si[8 * 512];
};
union SelOrMerge {
    float selT[CC * SEL_LD];
    MergeScratch m;
};

// K1, 768 blocks x 512 thr, block-specialized, Vt=8 + N-split:
//   blocks [0,256)   : argmin of 512 verts x 1024 pts (one half) -> cand
//                      (vg = bid>>1, h = bid&1; 8 waves x 128-pt chunks,
//                       Vt=8 verts/lane: 128 VALU-cyc per ds_read_b128 —
//                       LDS latency covered WITHIN the wave, pipe demand
//                       halved vs Vt=4; r10-r15 falsified the occupancy axis)
//   blocks [256,768) : MLP for 32 rows each -> mlp_out (r13-proven)
// 256 argmin blocks = exactly 1 per CU -> no MLP-drain imbalance tail.
// Bit-exact reference rounding (frozen since round 4):
//   sp = (rn(px^2)+rn(py^2))+rn(pz^2)
//   e2 = fma(2vz,pz, fma(2vy,py, rn(2vx*px))) == rn(2e)   (2x exact)
//   d2 = rn(rn(sv - e2) + sp)
//   strict < + ascending chunk merge -> first-index ties within half;
//   gather combines half0-first with strict < -> global first-index ties.
__global__ __launch_bounds__(512, 6) void argmin_mlp_kernel(
    const float* __restrict__ verts, const float* __restrict__ graph_pos,
    const float* __restrict__ processed, const float* __restrict__ W1,
    const float* __restrict__ b1, const float* __restrict__ W2,
    const float* __restrict__ b2, float* __restrict__ mlp_out,
    uint2* __restrict__ cand)
{
    __shared__ float4 pts[HALF];      // 16 KB
    __shared__ SelOrMerge u;          // 24 KB

    const int t = threadIdx.x;
    const int lane = t & 63;
    const int w = __builtin_amdgcn_readfirstlane(t >> 6);   // wave id 0..7

    if (blockIdx.x < 256) {
        // ================= ARGMIN BLOCK (512 verts, one point-half) ========
        const int vg = blockIdx.x >> 1;   // vertex group 0..127
        const int h  = blockIdx.x & 1;    // point half 0/1
        const int b  = vg >> 4;           // 16 groups per batch (V/512)
        const int v0 = (vg & 15) * 512;

        // stage this half's 1024 points with exact sp
        #pragma unroll
        for (int i = 0; i < 2; ++i) {
            int p = t + i * 512;          // 0..1023
            const float* g3 = graph_pos + ((size_t)b * NN + h * HALF + p) * 3;
            float px = g3[0], py = g3[1], pz = g3[2];
            float sp = __fadd_rn(__fadd_rn(__fmul_rn(px, px), __fmul_rn(py, py)),
                                 __fmul_rn(pz, pz));
            pts[p] = make_float4(px, py, pz, sp);
        }

        // vertex registers (Vt=8 per lane)
        float sv[8], tx[8], ty[8], tz[8];
        #pragma unroll
        for (int j = 0; j < 8; ++j) {
            int v = v0 + j * 64 + lane;
            const float* vp = verts + ((size_t)b * VV + v) * 3;
            float x = vp[0], y = vp[1], z = vp[2];
            sv[j] = __fadd_rn(__fadd_rn(__fmul_rn(x, x), __fmul_rn(y, y)),
                              __fmul_rn(z, z));
            tx[j] = x + x; ty[j] = y + y; tz[j] = z + z;   // exact 2x
        }
        __syncthreads();

        // scan: wave w covers chunk [w*128, w*128+128) of this half
        const float4* P = &pts[w * 128];
        float best[8];
        int bi[8];
        #pragma unroll
        for (int j = 0; j < 8; ++j) { best[j] = 3.4e38f; bi[j] = 0; }
        #pragma unroll 2
        for (int n = 0; n < 128; ++n) {
            float4 Q = P[n];   // ds_read_b128, same-addr broadcast (conflict-free)
            #pragma unroll
            for (int j = 0; j < 8; ++j) {
                float e2 = fmaf(tz[j], Q.z, fmaf(ty[j], Q.y, __fmul_rn(tx[j], Q.x)));
                float d2 = __fadd_rn(__fsub_rn(sv[j], e2), Q.w);
                if (d2 < best[j]) { best[j] = d2; bi[j] = n; }  // strict <: first idx
            }
        }

        __syncthreads();   // safe to alias u as merge scratch (selT untouched)
        #pragma unroll
        for (int j = 0; j < 8; ++j) {
            u.m.sd[w * 512 + j * 64 + lane] = best[j];
            u.m.si[w * 512 + j * 64 + lane] = (unsigned short)(bi[j] + w * 128);
        }
        __syncthreads();

        // final merge: thread t handles vertex v0+t (t<512 == all threads)
        {
            float bb = u.m.sd[t];
            int   ii = u.m.si[t];
            #pragma unroll
            for (int c = 1; c < 8; ++c) {       // ascending chunks: first-index ties
                float d = u.m.sd[c * 512 + t];
                int   i = u.m.si[c * 512 + t];
                if (d < bb) { bb = d; ii = i; }
            }
            cand[(size_t)h * (BB * VV) + (size_t)b * VV + v0 + t] =
                make_uint2(__float_as_uint(bb), (unsigned)(h * HALF + ii));
        }
    } else {
        // ================= MLP BLOCK (32 rows, r13-proven) =================
        const int mb = blockIdx.x - 256;      // 0..511
        const int row0 = mb * 32;

        #pragma unroll
        for (int i = 0; i < 8; ++i) {
            int flat = i * 512 + t;           // 0..4095
            int r = flat >> 7;                // 0..31
            int k = flat & 127;
            u.selT[k * SEL_LD + r] = processed[(size_t)(row0 + r) * CC + k];
        }
        __syncthreads();

        const int g = t & 31;                 // col group: 4 cols
        const int rb = t >> 5;                // row group: 2 rows, 0..15
        const int c0 = g * 4;
        const int r0 = rb * 2;

        float acc[2][4] = {{0.f, 0.f, 0.f, 0.f}, {0.f, 0.f, 0.f, 0.f}};
        #pragma unroll 4
        for (int k = 0; k < CC; ++k) {
            float4 wv = *(const float4*)(W1 + k * CC + c0);
            float2 av = *(const float2*)(&u.selT[k * SEL_LD + r0]);
            acc[0][0] = fmaf(av.x, wv.x, acc[0][0]);
            acc[0][1] = fmaf(av.x, wv.y, acc[0][1]);
            acc[0][2] = fmaf(av.x, wv.z, acc[0][2]);
            acc[0][3] = fmaf(av.x, wv.w, acc[0][3]);
            acc[1][0] = fmaf(av.y, wv.x, acc[1][0]);
            acc[1][1] = fmaf(av.y, wv.y, acc[1][1]);
            acc[1][2] = fmaf(av.y, wv.z, acc[1][2]);
            acc[1][3] = fmaf(av.y, wv.w, acc[1][3]);
        }

        float4 b1v = *(const float4*)(b1 + c0);
        float4 w2v = *(const float4*)(W2 + c0);
        float bias2 = b2[0];

        #pragma unroll
        for (int i = 0; i < 2; ++i) {
            float h0 = acc[i][0] + b1v.x; h0 = h0 > 0.f ? h0 : 0.f;
            float h1 = acc[i][1] + b1v.y; h1 = h1 > 0.f ? h1 : 0.f;
            float h2 = acc[i][2] + b1v.z; h2 = h2 > 0.f ? h2 : 0.f;
            float h3 = acc[i][3] + b1v.w; h3 = h3 > 0.f ? h3 : 0.f;
            float p = fmaf(h0, w2v.x, fmaf(h1, w2v.y, fmaf(h2, w2v.z, h3 * w2v.w)));
            // reduce across the 32 col-lanes (xor offsets <32 stay in half-wave)
            #pragma unroll
            for (int off = 1; off < 32; off <<= 1) p += __shfl_xor(p, off, 64);
            if (g == 0) mlp_out[row0 + r0 + i] = p + bias2;
        }
    }
}

// K2: combine the two half-candidates (half0 first + strict < == global
// first-index tie-break) and gather mlp_out. Everything L2-hot.
__global__ __launch_bounds__(256) void gather_kernel(
    const float* __restrict__ mlp_out, const uint2* __restrict__ cand,
    float* __restrict__ out)
{
    const int gid = blockIdx.x * 256 + threadIdx.x;   // 0..65535
    const int b = gid >> 13;                          // / VV
    uint2 c0 = cand[gid];
    uint2 c1 = cand[BB * VV + gid];
    float d0 = __uint_as_float(c0.x);
    float d1 = __uint_as_float(c1.x);
    unsigned ii = (d1 < d0) ? c1.y : c0.y;            // strict: half0 wins ties
    out[gid] = mlp_out[b * NN + (int)ii];
}

extern "C" void kernel_launch(void* const* d_in, const int* in_sizes, int n_in,
                              void* d_out, int out_size, void* d_ws, size_t ws_size,
                              hipStream_t stream) {
    const float* verts     = (const float*)d_in[0];
    const float* graph_pos = (const float*)d_in[1];
    const float* processed = (const float*)d_in[2];
    const float* W1        = (const float*)d_in[3];
    const float* b1        = (const float*)d_in[4];
    const float* W2        = (const float*)d_in[5];
    const float* b2        = (const float*)d_in[6];
    float* out = (float*)d_out;

    float* mlp_out = (float*)d_ws;                              // 64 KB
    uint2* cand    = (uint2*)((char*)d_ws + BB * NN * 4);       // 2 x 512 KB

    hipLaunchKernelGGL(argmin_mlp_kernel, dim3(768), dim3(512), 0, stream,
                       verts, graph_pos, processed, W1, b1, W2, b2,
                       mlp_out, cand);
    hipLaunchKernelGGL(gather_kernel, dim3((BB * VV) / 256), dim3(256), 0, stream,
                       mlp_out, cand, out);
}

// Round 17
// 103.403 us; speedup vs baseline: 1.2103x; 1.0365x over previous
//
#include <hip/hip_runtime.h>

// Problem constants (B=8, V=8192, N=2048, C=128)
#define BB 8
#define VV 8192
#define NN 2048
#define CC 128
#define SEL_LD 34   // 32-row selT tile leading dim (even -> 8B-aligned float2 reads)

// Shared memory (~49 KB -> 3 blocks/CU, 24 waves/CU):
//   pts[2048] float4        : 32 KB   (argmin blocks only)
//   union {
//     selT[128*34] float    : 17 KB   (MLP blocks)
//     { sd, si }            : 12 KB   (argmin merge scratch: 8 chunks x 256)
//   }
// SESSION OPTIMUM (r13 = 102.4 us). Falsified axes: occupancy 2/3/4 blk/CU,
// VGPR budget, manual SWP, scalar-pipe point feed, N-split, Vt=2/8.
// Vt=4 + 8-wave argmin blocks + mixed-in MLP blocks is the measured best.
struct MergeScratch {
    float sd[8 * 256];
    unsigned short si[8 * 256];
};
union SelOrMerge {
    float selT[CC * SEL_LD];
    MergeScratch m;
};

// K1, 768 blocks x 512 thr, block-specialized:
//   blocks [0,256)   : argmin for 256 vertices each -> idx_out (u16)
//   blocks [256,768) : MLP for 32 rows each         -> mlp_out
// Bit-exact reference rounding (frozen since round 4):
//   sp = (rn(px^2)+rn(py^2))+rn(pz^2)
//   e2 = fma(2vz,pz, fma(2vy,py, rn(2vx*px))) == rn(2e)   (2x exact)
//   d2 = rn(rn(sv - e2) + sp)
//   strict < + ascending chunk merge -> first-index tie-break.
__global__ __launch_bounds__(512, 6) void argmin_mlp_kernel(
    const float* __restrict__ verts, const float* __restrict__ graph_pos,
    const float* __restrict__ processed, const float* __restrict__ W1,
    const float* __restrict__ b1, const float* __restrict__ W2,
    const float* __restrict__ b2, float* __restrict__ mlp_out,
    unsigned short* __restrict__ idx_out)
{
    __shared__ float4 pts[NN];        // 32 KB
    __shared__ SelOrMerge u;          // 17 KB

    const int t = threadIdx.x;
    const int lane = t & 63;
    const int w = __builtin_amdgcn_readfirstlane(t >> 6);   // wave id 0..7

    if (blockIdx.x < 256) {
        // ================= ARGMIN BLOCK =================
        const int bid = blockIdx.x;
        const int b = bid >> 5;           // 32 blocks per batch
        const int v0 = (bid & 31) * 256;

        // stage pts (2048 points of batch b) with exact sp
        #pragma unroll
        for (int i = 0; i < 4; ++i) {
            int p = t + i * 512;
            const float* g3 = graph_pos + ((size_t)b * NN + p) * 3;
            float px = g3[0], py = g3[1], pz = g3[2];
            float sp = __fadd_rn(__fadd_rn(__fmul_rn(px, px), __fmul_rn(py, py)),
                                 __fmul_rn(pz, pz));
            pts[p] = make_float4(px, py, pz, sp);
        }

        // vertex registers (Vt=4 per lane)
        float sv[4], tx[4], ty[4], tz[4];
        #pragma unroll
        for (int j = 0; j < 4; ++j) {
            int v = v0 + j * 64 + lane;
            const float* vp = verts + ((size_t)b * VV + v) * 3;
            float x = vp[0], y = vp[1], z = vp[2];
            sv[j] = __fadd_rn(__fadd_rn(__fmul_rn(x, x), __fmul_rn(y, y)),
                              __fmul_rn(z, z));
            tx[j] = x + x; ty[j] = y + y; tz[j] = z + z;   // exact 2x
        }
        __syncthreads();

        // scan: wave w covers point chunk [w*256, w*256+256)
        const float4* P = &pts[w * 256];
        float best[4] = {3.4e38f, 3.4e38f, 3.4e38f, 3.4e38f};
        int bi[4] = {0, 0, 0, 0};
        #pragma unroll 4
        for (int n = 0; n < 256; ++n) {
            float4 Q = P[n];   // ds_read_b128, same-addr broadcast (conflict-free)
            #pragma unroll
            for (int j = 0; j < 4; ++j) {
                float e2 = fmaf(tz[j], Q.z, fmaf(ty[j], Q.y, __fmul_rn(tx[j], Q.x)));
                float d2 = __fadd_rn(__fsub_rn(sv[j], e2), Q.w);
                if (d2 < best[j]) { best[j] = d2; bi[j] = n; }  // strict <: first idx
            }
        }

        __syncthreads();   // safe to alias u as merge scratch
        #pragma unroll
        for (int j = 0; j < 4; ++j) {
            u.m.sd[w * 256 + j * 64 + lane] = best[j];
            u.m.si[w * 256 + j * 64 + lane] = (unsigned short)(bi[j] + w * 256);
        }
        __syncthreads();

        if (t < 256) {
            float bb = u.m.sd[t];
            int   ii = u.m.si[t];
            #pragma unroll
            for (int c = 1; c < 8; ++c) {       // ascending chunks: first-index ties
                float d = u.m.sd[c * 256 + t];
                int   i = u.m.si[c * 256 + t];
                if (d < bb) { bb = d; ii = i; }
            }
            idx_out[(size_t)b * VV + v0 + t] = (unsigned short)ii;
        }
    } else {
        // ================= MLP BLOCK (32 rows) =================
        const int mb = blockIdx.x - 256;      // 0..511
        const int row0 = mb * 32;

        #pragma unroll
        for (int i = 0; i < 8; ++i) {
            int flat = i * 512 + t;           // 0..4095
            int r = flat >> 7;                // 0..31
            int k = flat & 127;
            u.selT[k * SEL_LD + r] = processed[(size_t)(row0 + r) * CC + k];
        }
        __syncthreads();

        const int g = t & 31;                 // col group: 4 cols
        const int rb = t >> 5;                // row group: 2 rows, 0..15
        const int c0 = g * 4;
        const int r0 = rb * 2;

        float acc[2][4] = {{0.f, 0.f, 0.f, 0.f}, {0.f, 0.f, 0.f, 0.f}};
        #pragma unroll 4
        for (int k = 0; k < CC; ++k) {
            float4 wv = *(const float4*)(W1 + k * CC + c0);
            float2 av = *(const float2*)(&u.selT[k * SEL_LD + r0]);
            acc[0][0] = fmaf(av.x, wv.x, acc[0][0]);
            acc[0][1] = fmaf(av.x, wv.y, acc[0][1]);
            acc[0][2] = fmaf(av.x, wv.z, acc[0][2]);
            acc[0][3] = fmaf(av.x, wv.w, acc[0][3]);
            acc[1][0] = fmaf(av.y, wv.x, acc[1][0]);
            acc[1][1] = fmaf(av.y, wv.y, acc[1][1]);
            acc[1][2] = fmaf(av.y, wv.z, acc[1][2]);
            acc[1][3] = fmaf(av.y, wv.w, acc[1][3]);
        }

        float4 b1v = *(const float4*)(b1 + c0);
        float4 w2v = *(const float4*)(W2 + c0);
        float bias2 = b2[0];

        #pragma unroll
        for (int i = 0; i < 2; ++i) {
            float h0 = acc[i][0] + b1v.x; h0 = h0 > 0.f ? h0 : 0.f;
            float h1 = acc[i][1] + b1v.y; h1 = h1 > 0.f ? h1 : 0.f;
            float h2 = acc[i][2] + b1v.z; h2 = h2 > 0.f ? h2 : 0.f;
            float h3 = acc[i][3] + b1v.w; h3 = h3 > 0.f ? h3 : 0.f;
            float p = fmaf(h0, w2v.x, fmaf(h1, w2v.y, fmaf(h2, w2v.z, h3 * w2v.w)));
            // reduce across the 32 col-lanes (xor offsets <32 stay in half-wave)
            #pragma unroll
            for (int off = 1; off < 32; off <<= 1) p += __shfl_xor(p, off, 64);
            if (g == 0) mlp_out[row0 + r0 + i] = p + bias2;
        }
    }
}

// K2: out[b,v] = mlp_out[b*NN + idx[b,v]]. mlp_out is 8 KB/batch -> L2 hot.
__global__ __launch_bounds__(256) void gather_kernel(
    const float* __restrict__ mlp_out, const unsigned short* __restrict__ idx,
    float* __restrict__ out)
{
    const int gid = blockIdx.x * 256 + threadIdx.x;   // 0..65535
    const int b = gid >> 13;                          // / VV
    out[gid] = mlp_out[b * NN + (int)idx[gid]];
}

extern "C" void kernel_launch(void* const* d_in, const int* in_sizes, int n_in,
                              void* d_out, int out_size, void* d_ws, size_t ws_size,
                              hipStream_t stream) {
    const float* verts     = (const float*)d_in[0];
    const float* graph_pos = (const float*)d_in[1];
    const float* processed = (const float*)d_in[2];
    const float* W1        = (const float*)d_in[3];
    const float* b1        = (const float*)d_in[4];
    const float* W2        = (const float*)d_in[5];
    const float* b2        = (const float*)d_in[6];
    float* out = (float*)d_out;

    float* mlp_out       = (float*)d_ws;                                 // 64 KB
    unsigned short* idxb = (unsigned short*)((char*)d_ws + BB * NN * 4); // 128 KB

    hipLaunchKernelGGL(argmin_mlp_kernel, dim3(768), dim3(512), 0, stream,
                       verts, graph_pos, processed, W1, b1, W2, b2,
                       mlp_out, idxb);
    hipLaunchKernelGGL(gather_kernel, dim3((BB * VV) / 256), dim3(256), 0, stream,
                       mlp_out, idxb, out);
}